// Round 4
// baseline (492.612 us; speedup 1.0000x reference)
//
#include <hip/hip_runtime.h>
#include <math.h>

// ---------- types / helpers ----------
typedef __attribute__((ext_vector_type(8))) short short8;   // 8 bf16 (4 VGPRs)
typedef __attribute__((ext_vector_type(4))) float f32x4;    // MFMA acc

#define MFMA16(a, b, c) __builtin_amdgcn_mfma_f32_16x16x32_bf16((a), (b), (c), 0, 0, 0)

// async global->LDS, 16B per lane. LDS dest is wave-uniform base + lane*16;
// the GLOBAL source address is per-lane -> swizzle the source for free.
__device__ inline void gl_lds16(const void* g, void* l) {
  __builtin_amdgcn_global_load_lds(
      (const __attribute__((address_space(1))) void*)g,
      (__attribute__((address_space(3))) void*)l, 16, 0, 0);
}

__device__ inline unsigned int pack2(float lo, float hi) {
  unsigned int ulo = __float_as_uint(lo), uhi = __float_as_uint(hi);
  return (uhi & 0xFFFF0000u) | (ulo >> 16);
}
__device__ inline unsigned short f2bf_r(float f) {
  return (unsigned short)((__float_as_uint(f) + 0x8000u) >> 16);
}
__device__ inline float bf2f(unsigned short h) {
  return __uint_as_float(((unsigned int)h) << 16);
}

// ---------- K0: merged weight repack ----------
// blocks 0..95:   W1 [3,2048,128] f32 -> W1bt [384,2048] bf16 (B^T, k-contiguous)
// blocks 96..287: W2 [3,128,128] f32  -> W2t  [j][d][c]  bf16 (transposed)
__global__ __launch_bounds__(256) void k_repack(const float* __restrict__ W1,
                                                const float* __restrict__ W2,
                                                unsigned short* __restrict__ W1bt,
                                                unsigned short* __restrict__ W2t) {
  __shared__ float tile[64 * 128];   // 32 KB
  const int b = blockIdx.x, tid = threadIdx.x;
  if (b < 96) {
    const int k = b >> 5, et = b & 31;
    const int e0 = et * 64;
    const float* src = W1 + (size_t)k * 262144 + (size_t)e0 * 128;
#pragma unroll
    for (int i = 0; i < 8; ++i) {
      int idx4 = tid + i * 256;
      ((f32x4*)tile)[idx4] = ((const f32x4*)src)[idx4];
    }
    __syncthreads();
#pragma unroll
    for (int i = 0; i < 4; ++i) {
      int item = tid + i * 256;
      int c = item >> 3, eo = (item & 7) * 8;
      union { unsigned short h[8]; uint4 v; } t;
#pragma unroll
      for (int u = 0; u < 8; ++u) t.h[u] = f2bf_r(tile[(eo + u) * 128 + c]);
      *(uint4*)(W1bt + (size_t)(k * 128 + c) * 2048 + e0 + eo) = t.v;
    }
  } else {
    int idx = (b - 96) * 256 + tid;                 // 49152
    int j = idx >> 14, r = idx & 16383, d = r >> 7, c = r & 127;
    W2t[idx] = f2bf_r(W2[(size_t)j * 16384 + (size_t)c * 128 + d]);
  }
}

// ---------- K0b: X transpose+convert ----------
// X f32 [32768][2048] -> Xbt bf16 [64 chunks][32784 rows][32], row idx = logical+4.
// Coalesced row-major reads -> LDS (xor-swizzled) -> contiguous chunk-major writes.
// Purpose: k_fused's A-staging becomes CONTIGUOUS (the 128B-per-8KB-stride DRAM
// pattern was capping HBM at ~1 TB/s = the real r0-r3 bottleneck), bytes halve
// (bf16), and Xbt is L3-resident-dirty when k_fused runs.
__global__ __launch_bounds__(256) void k_xpack(const float* __restrict__ X,
                                               unsigned short* __restrict__ Xbt) {
  __shared__ float tile[64 * 256];                  // 64 KB, word c stored at c^((row&3)<<3)
  const int b = blockIdx.x, tid = threadIdx.x;
  const int rbase = b * 64;
  for (int kg = 0; kg < 8; ++kg) {
    __syncthreads();                                // LDS reuse fence (iter>0)
    // load 64 rows x 256 f32, fully coalesced (1 KB contiguous per wave-instr)
#pragma unroll
    for (int i = 0; i < 16; ++i) {
      int item = tid + i * 256;                     // 4096 16B-units
      int row = item >> 6, c16 = item & 63;
      f32x4 v = *(const f32x4*)(X + (size_t)(rbase + row) * 2048 + kg * 256 + c16 * 4);
      int c0 = (c16 * 4) ^ ((row & 3) << 3);
      *(f32x4*)&tile[row * 256 + c0] = v;
    }
    __syncthreads();
    // write 8 K-chunks: chunk tc -> Xbt[kg*8+tc][rbase+4+row][32], contiguous 4 KB
#pragma unroll
    for (int tc = 0; tc < 8; ++tc) {
      int row2 = tid >> 2, c2 = (tid & 3) * 8;
      int sw = (row2 & 3) << 3;
      const float* p = &tile[row2 * 256 + ((tc * 32 + c2) ^ sw)];
      f32x4 a = *(const f32x4*)p;
      f32x4 bb = *(const f32x4*)(p + 4);
      union { unsigned int u[4]; uint4 v; } t;
      t.u[0] = pack2(a[0], a[1]);  t.u[1] = pack2(a[2], a[3]);
      t.u[2] = pack2(bb[0], bb[1]); t.u[3] = pack2(bb[2], bb[3]);
      *(uint4*)(Xbt + ((size_t)(kg * 8 + tc) * 32784 + rbase + 4 + row2) * 32 + c2) = t.v;
    }
  }
  // zero pad rows (idx 0..3 and 32772..32783) so halo reads are defined
  if (b == 0) {
    for (int i = tid; i < 4096; i += 256) {         // 64 chunks x 4 rows x 16 uints
      int t = i >> 6, rr = (i >> 4) & 3, c = (i & 15) * 2;
      *(unsigned int*)(Xbt + ((size_t)t * 32784 + rr) * 32 + c) = 0u;
    }
  } else if (b == 511) {
    for (int i = tid; i < 12288; i += 256) {        // 64 chunks x 12 rows x 16 uints
      int t = i / 192, rem = i - t * 192;
      int rr = 32772 + (rem >> 4), c = (rem & 15) * 2;
      *(unsigned int*)(Xbt + ((size_t)t * 32784 + rr) * 32 + c) = 0u;
    }
  }
}

// ---------- K1 (fast): fused stage1 GEMM + tap-sum/tanh + stage2 GEMM + log-softmax ----------
// 512 blocks x 256 thr (4 waves), 64 out rows/block, 2 blocks/CU. A comes from Xbt
// (contiguous bf16, no in-loop f32->bf16 pack). BK=32, dbuf (2 x 29696 B), depth-1
// counted pipeline: raw s_barrier + vmcnt(0)-on-own-prior-stage; stage(t+1) issued
// before compute(t) so loads have a full compute phase in flight.
__global__ __launch_bounds__(256, 2) void k_fused_x(const unsigned short* __restrict__ Xbt,
                                                    const unsigned short* __restrict__ Bt,
                                                    const unsigned short* __restrict__ W2t,
                                                    const float* __restrict__ b1,
                                                    const float* __restrict__ b2,
                                                    float* __restrict__ out) {
  // per buffer: A 80 rows x 64 B (5120 B, slot s at s^((row>>1)&3)),
  //             B 384 cols x 64 B at +5120 (24576 B, slot s at s^((col>>1)&3))
  constexpr int BUF = 29696;
  __shared__ __align__(16) char smem[63744];
  unsigned short* Yt = (unsigned short*)smem;             // phase B: 80 x 392 bf16 (62,720 B)
  float* zbuf = (float*)(smem + 62720);                   // 2 x 128 f32

  const int r0 = blockIdx.x * 64;
  const int tid = threadIdx.x, wave = tid >> 6, lane = tid & 63;
  const int mrow = lane & 15, quad = lane >> 4;
  const int srcsl = (lane & 3) ^ ((lane >> 3) & 3);       // source-slot swizzle (A and B)

  // A staging: 5 loads of 16 rows (1 KB each). wave w -> load w; wave 0 also load 4.
  // A-LDS row i (0..79) <-> Xbt row idx r0+i (logical r0-4+i; pads are zeroed).
  const unsigned short* axp[2];
  axp[0] = Xbt + ((size_t)r0 + wave * 16 + (lane >> 2)) * 32 + srcsl * 8;
  axp[1] = Xbt + ((size_t)r0 + 64 + (lane >> 2)) * 32 + srcsl * 8;   // wave 0 only
  // B staging: 24 loads (16 cols each), wave w -> loads w*6..w*6+5
  const unsigned short* bgp[6];
#pragma unroll
  for (int jj = 0; jj < 6; ++jj) {
    int col = (wave * 6 + jj) * 16 + (lane >> 2);
    bgp[jj] = Bt + (size_t)col * 2048 + srcsl * 8;
  }

  f32x4 acc[5][6] = {};   // 80 logical rows (5 rt) x 96 cols (6 ct) per wave

  auto stage = [&](char* base) {
    gl_lds16(axp[0], base + wave * 1024);
    if (wave == 0) gl_lds16(axp[1], base + 4 * 1024);
#pragma unroll
    for (int jj = 0; jj < 6; ++jj)
      gl_lds16(bgp[jj], base + 5120 + (wave * 6 + jj) * 1024);
    axp[0] += (size_t)32784 * 32;                   // next K-chunk plane
    axp[1] += (size_t)32784 * 32;
#pragma unroll
    for (int jj = 0; jj < 6; ++jj) bgp[jj] += 32;   // next 32 bf16 along k
  };

  auto compute = [&](const char* base) {
    const unsigned short* Ab = (const unsigned short*)base;
    const unsigned short* Bb = (const unsigned short*)(base + 5120);
    const int sl = (quad ^ ((mrow >> 1) & 3)) * 8;
    short8 af[5];
#pragma unroll
    for (int rt = 0; rt < 5; ++rt)
      af[rt] = *(const short8*)(Ab + (rt * 16 + mrow) * 32 + sl);
#pragma unroll
    for (int ct = 0; ct < 6; ++ct) {
      int col = wave * 96 + ct * 16 + mrow;
      short8 bf = *(const short8*)(Bb + col * 32 + sl);
#pragma unroll
      for (int rt = 0; rt < 5; ++rt)
        acc[rt][ct] = MFMA16(af[rt], bf, acc[rt][ct]);
    }
  };

  stage((char*)smem);                               // chunk 0 -> buf 0
#pragma unroll 2
  for (int t = 0; t < 64; ++t) {
    asm volatile("s_waitcnt vmcnt(0)" ::: "memory"); // own stage(t) arrived
    __builtin_amdgcn_s_barrier();                    // all stage(t) visible; all compute(t-1) done
    __builtin_amdgcn_sched_barrier(0);
    if (t < 63) stage(smem + ((t + 1) & 1) * BUF);   // in flight under compute(t)
    compute(smem + (t & 1) * BUF);
  }
  __syncthreads();                                   // buffers die; Yt phase begins

  // ---- spill acc -> Yt (bf16). Yt row i <-> Y global row r0-4+i; stride 392 ----
#pragma unroll
  for (int rt = 0; rt < 5; ++rt)
#pragma unroll
    for (int ct = 0; ct < 6; ++ct)
#pragma unroll
      for (int rg = 0; rg < 4; ++rg) {
        int l = rt * 16 + quad * 4 + rg;
        int col = wave * 96 + ct * 16 + mrow;
        Yt[l * 392 + col] = f2bf_r(acc[rt][ct][rg]);
      }
  __syncthreads();

  // ---- H[p]=tanh(sum taps + cnt*b1), p in [r0-2, r0+63]; store at dead tap-2 slot ----
  for (int idx = tid; idx < 66 * 128; idx += 256) {
    int hl = idx >> 7, c = idx & 127;
    int p = r0 - 2 + hl;
    int i = hl + 2;                                   // tap-0 Yt row
    float h = 0.f;
    if (p >= 0) {
      float s = bf2f(Yt[i * 392 + c]);
      float cnt = 1.f;
      if (p >= 1) { s += bf2f(Yt[(i - 1) * 392 + 128 + c]); cnt += 1.f; }
      if (p >= 2) { s += bf2f(Yt[(i - 2) * 392 + 256 + c]); cnt += 1.f; }
      h = tanhf(fmaf(cnt, b1[c], s));
    }
    Yt[(i - 2) * 392 + 256 + c] = f2bf_r(h);          // = Yt[hl][256+c], holds H[r0-2+hl]
  }
  __syncthreads();

  // ---- stage-2: Z rows r0+wave*16..+15 ----
  f32x4 acc2[8] = {};
#pragma unroll
  for (int j = 0; j < 3; ++j) {
#pragma unroll
    for (int kk = 0; kk < 4; ++kk) {
      short8 a0 = *(const short8*)&Yt[(wave * 16 + mrow + j) * 392 + 256 + kk * 32 + quad * 8];
      const unsigned short* wp = W2t + (size_t)(j * 128 + mrow) * 128 + kk * 32 + quad * 8;
#pragma unroll
      for (int ct = 0; ct < 8; ++ct)
        acc2[ct] = MFMA16(a0, *(const short8*)(wp + ct * 16 * 128), acc2[ct]);
    }
  }

  // ---- log-softmax per row ----
#pragma unroll
  for (int rg = 0; rg < 4; ++rg) {
    float z[8]; float m = -1e30f;
#pragma unroll
    for (int ct = 0; ct < 8; ++ct) {
      z[ct] = acc2[ct][rg] + 3.f * b2[ct * 16 + mrow];
      m = fmaxf(m, z[ct]);
    }
#pragma unroll
    for (int off = 1; off < 16; off <<= 1) m = fmaxf(m, __shfl_xor(m, off, 64));
    float s = 0.f;
#pragma unroll
    for (int ct = 0; ct < 8; ++ct) s += __expf(z[ct] - m);
#pragma unroll
    for (int off = 1; off < 16; off <<= 1) s += __shfl_xor(s, off, 64);
    float lse = m + __logf(s);
    int grow = r0 + wave * 16 + quad * 4 + rg;
    if (grow >= 2) {
      float* op = out + (size_t)grow * 128 + mrow;
#pragma unroll
      for (int ct = 0; ct < 8; ++ct) op[ct * 16] = z[ct] - lse;
    }
  }

  // ---- fallback rows 0,1 (block 0) ----
  if (blockIdx.x == 0) {
    __syncthreads();
    int row = tid >> 7, d = tid & 127;
    zbuf[row * 128 + d] = tanhf(bf2f(Yt[(row + 4) * 392 + d]) + b1[d]);
    __syncthreads();
    float zv = b2[d];
    for (int c = 0; c < 128; ++c)
      zv = fmaf(zbuf[row * 128 + c], bf2f(W2t[(size_t)d * 128 + c]), zv);
    __syncthreads();
    zbuf[row * 128 + d] = zv;
    __syncthreads();
    float m = -1e30f;
    for (int c = 0; c < 128; ++c) m = fmaxf(m, zbuf[row * 128 + c]);
    float s = 0.f;
    for (int c = 0; c < 128; ++c) s += __expf(zbuf[row * 128 + c] - m);
    out[(size_t)row * 128 + d] = zv - m - __logf(s);
  }
}

// ---------- K1 (fallback, round-3 verbatim): used when ws_size can't hold Xbt ----------
__global__ __launch_bounds__(512, 2) void k_fused_fb(const float* __restrict__ X,
                                                     const unsigned short* __restrict__ Bt,
                                                     const unsigned short* __restrict__ W2t,
                                                     const float* __restrict__ b1,
                                                     const float* __restrict__ b2,
                                                     float* __restrict__ out) {
  constexpr int BUF = 43008, BOFF = 18432;
  __shared__ __align__(16) char smem[3 * 43008];
  unsigned short* Yt = (unsigned short*)smem;
  float* zbuf = (float*)(smem + 106624);

  const int r0 = blockIdx.x * 128;
  const int tid = threadIdx.x, wave = tid >> 6, lane = tid & 63;
  const int mrow = lane & 15, quad = lane >> 4;
  const int wr = wave >> 2, wc = wave & 3;

  const float* agp[3];
  {
    const int Ls[3] = { wave, wave + 8, 16 + wave };
#pragma unroll
    for (int jj = 0; jj < 3; ++jj) {
      int u = Ls[jj] * 64 + lane;
      int pl = u / 144, rr = u - pl * 144;
      if (pl > 7) pl = 7;
      int g = r0 - 4 + rr;
      if (g < 0) g = 0;
      if (g > 32767) g = 32767;
      agp[jj] = X + (size_t)g * 2048 + pl * 4;
    }
  }
  const unsigned short* bgp[3];
#pragma unroll
  for (int jj = 0; jj < 3; ++jj) {
    int col = (wave * 3 + jj) * 16 + (lane >> 2);
    int kc = (lane & 3) ^ ((lane >> 3) & 3);
    bgp[jj] = Bt + (size_t)col * 2048 + kc * 8;
  }

  f32x4 acc[5][6] = {};

  auto stage = [&](char* base) {
    gl_lds16(agp[0], base + wave * 1024);
    gl_lds16(agp[1], base + (wave + 8) * 1024);
    if (wave < 2) gl_lds16(agp[2], base + (16 + wave) * 1024);
#pragma unroll
    for (int jj = 0; jj < 3; ++jj)
      gl_lds16(bgp[jj], base + BOFF + (wave * 3 + jj) * 1024);
#pragma unroll
    for (int jj = 0; jj < 3; ++jj) agp[jj] += 32;
#pragma unroll
    for (int jj = 0; jj < 3; ++jj) bgp[jj] += 32;
  };

  auto compute = [&](const char* base) {
    const char* Ab = base;
    const unsigned short* Bb = (const unsigned short*)(base + BOFF);
    short8 af[5];
#pragma unroll
    for (int rt = 0; rt < 5; ++rt) {
      int row = wr * 80 + rt * 16 + mrow;
      f32x4 x0 = *(const f32x4*)(Ab + (quad * 2) * 2304 + row * 16);
      f32x4 x1 = *(const f32x4*)(Ab + (quad * 2 + 1) * 2304 + row * 16);
      union { unsigned int u[4]; short8 v; } tt;
      tt.u[0] = pack2(x0[0], x0[1]); tt.u[1] = pack2(x0[2], x0[3]);
      tt.u[2] = pack2(x1[0], x1[1]); tt.u[3] = pack2(x1[2], x1[3]);
      af[rt] = tt.v;
    }
#pragma unroll
    for (int ct = 0; ct < 6; ++ct) {
      int col = wc * 96 + ct * 16 + mrow;
      int slot = quad ^ ((mrow >> 1) & 3);
      short8 bf = *(const short8*)(Bb + col * 32 + slot * 8);
#pragma unroll
      for (int rt = 0; rt < 5; ++rt)
        acc[rt][ct] = MFMA16(af[rt], bf, acc[rt][ct]);
    }
  };

  stage(smem);
  stage(smem + BUF);

  int cur = 0, nx2 = 2;
  for (int t = 0; t < 63; ++t) {
    if (wave < 2) asm volatile("s_waitcnt vmcnt(6)" ::: "memory");
    else          asm volatile("s_waitcnt vmcnt(5)" ::: "memory");
    __builtin_amdgcn_s_barrier();
    __builtin_amdgcn_sched_barrier(0);
    if (t < 62) stage(smem + nx2 * BUF);
    compute(smem + cur * BUF);
    cur = (cur == 2) ? 0 : cur + 1;
    nx2 = (nx2 == 2) ? 0 : nx2 + 1;
  }
  asm volatile("s_waitcnt vmcnt(0)" ::: "memory");
  __builtin_amdgcn_s_barrier();
  __builtin_amdgcn_sched_barrier(0);
  compute(smem + cur * BUF);
  __syncthreads();

#pragma unroll
  for (int rt = 0; rt < 5; ++rt)
#pragma unroll
    for (int ct = 0; ct < 6; ++ct)
#pragma unroll
      for (int rg = 0; rg < 4; ++rg) {
        int l = wr * 80 + rt * 16 + quad * 4 + rg;
        int col = wc * 96 + ct * 16 + mrow;
        if (l < 136) Yt[l * 392 + col] = f2bf_r(acc[rt][ct][rg]);
      }
  __syncthreads();

  for (int idx = tid; idx < 130 * 128; idx += 512) {
    int hl = idx >> 7, c = idx & 127;
    int p = r0 - 2 + hl;
    int i = hl + 2;
    float h = 0.f;
    if (p >= 0) {
      float s = bf2f(Yt[i * 392 + c]);
      float cnt = 1.f;
      if (p >= 1) { s += bf2f(Yt[(i - 1) * 392 + 128 + c]); cnt += 1.f; }
      if (p >= 2) { s += bf2f(Yt[(i - 2) * 392 + 256 + c]); cnt += 1.f; }
      h = tanhf(fmaf(cnt, b1[c], s));
    }
    Yt[(i - 2) * 392 + 256 + c] = f2bf_r(h);
  }
  __syncthreads();

  f32x4 acc2[8] = {};
#pragma unroll
  for (int j = 0; j < 3; ++j) {
#pragma unroll
    for (int kk = 0; kk < 4; ++kk) {
      short8 a0 = *(const short8*)&Yt[(wave * 16 + mrow + j) * 392 + 256 + kk * 32 + quad * 8];
      const unsigned short* wp = W2t + (size_t)(j * 128 + mrow) * 128 + kk * 32 + quad * 8;
#pragma unroll
      for (int ct = 0; ct < 8; ++ct)
        acc2[ct] = MFMA16(a0, *(const short8*)(wp + ct * 16 * 128), acc2[ct]);
    }
  }

#pragma unroll
  for (int rg = 0; rg < 4; ++rg) {
    float z[8]; float m = -1e30f;
#pragma unroll
    for (int ct = 0; ct < 8; ++ct) {
      z[ct] = acc2[ct][rg] + 3.f * b2[ct * 16 + mrow];
      m = fmaxf(m, z[ct]);
    }
#pragma unroll
    for (int off = 1; off < 16; off <<= 1) m = fmaxf(m, __shfl_xor(m, off, 64));
    float s = 0.f;
#pragma unroll
    for (int ct = 0; ct < 8; ++ct) s += __expf(z[ct] - m);
#pragma unroll
    for (int off = 1; off < 16; off <<= 1) s += __shfl_xor(s, off, 64);
    float lse = m + __logf(s);
    int grow = r0 + wave * 16 + quad * 4 + rg;
    if (grow >= 2) {
      float* op = out + (size_t)grow * 128 + mrow;
#pragma unroll
      for (int ct = 0; ct < 8; ++ct) op[ct * 16] = z[ct] - lse;
    }
  }

  if (blockIdx.x == 0) {
    __syncthreads();
    int row = tid >> 7, d = tid & 127;
    if (tid < 256)
      zbuf[row * 128 + d] = tanhf(bf2f(Yt[(row + 4) * 392 + d]) + b1[d]);
    __syncthreads();
    float zv = 0.f;
    if (tid < 256) {
      zv = b2[d];
      for (int c = 0; c < 128; ++c)
        zv = fmaf(zbuf[row * 128 + c], bf2f(W2t[(size_t)d * 128 + c]), zv);
    }
    __syncthreads();
    if (tid < 256) zbuf[row * 128 + d] = zv;
    __syncthreads();
    if (tid < 256) {
      float m = -1e30f;
      for (int c = 0; c < 128; ++c) m = fmaxf(m, zbuf[row * 128 + c]);
      float s = 0.f;
      for (int c = 0; c < 128; ++c) s += __expf(zbuf[row * 128 + c] - m);
      out[(size_t)row * 128 + d] = zv - m - __logf(s);
    }
  }
}

// ---------- launch ----------
extern "C" void kernel_launch(void* const* d_in, const int* in_sizes, int n_in,
                              void* d_out, int out_size, void* d_ws, size_t ws_size,
                              hipStream_t stream) {
  const float* X  = (const float*)d_in[0];   // [32768, 1, 2048]
  const float* W1 = (const float*)d_in[1];   // [3, 2048, 128]
  const float* b1 = (const float*)d_in[2];   // [1, 128]
  const float* W2 = (const float*)d_in[3];   // [3, 128, 128]
  const float* b2 = (const float*)d_in[4];   // [1, 128]
  float* out = (float*)d_out;                // [32768, 1, 128] fp32

  unsigned short* W1bt = (unsigned short*)d_ws;                    // 1,572,864 B
  unsigned short* W2t  = (unsigned short*)((char*)d_ws + 1572864); // 98,304 B
  unsigned short* Xbt  = (unsigned short*)((char*)d_ws + 1703936); // 134,283,264 B
  const size_t need = 1703936 + (size_t)64 * 32784 * 64;

  k_repack<<<288, 256, 0, stream>>>(W1, W2, W1bt, W2t);
  if (ws_size >= need) {
    k_xpack<<<512, 256, 0, stream>>>(X, Xbt);
    k_fused_x<<<512, 256, 0, stream>>>(Xbt, W1bt, W2t, b1, b2, out);
  } else {
    k_fused_fb<<<256, 512, 0, stream>>>(X, W1bt, W2t, b1, b2, out);
  }
}

// Round 5
// 421.943 us; speedup vs baseline: 1.1675x; 1.1675x over previous
//
#include <hip/hip_runtime.h>
#include <math.h>

// ---------- types / helpers ----------
typedef __attribute__((ext_vector_type(8))) short short8;   // 8 bf16 (4 VGPRs)
typedef __attribute__((ext_vector_type(4))) float f32x4;    // MFMA acc

#define MFMA16(a, b, c) __builtin_amdgcn_mfma_f32_16x16x32_bf16((a), (b), (c), 0, 0, 0)

// async global->LDS, 16B per lane. LDS dest is wave-uniform base + lane*16;
// the GLOBAL source address is per-lane -> swizzle the source for free.
__device__ inline void gl_lds16(const void* g, void* l) {
  __builtin_amdgcn_global_load_lds(
      (const __attribute__((address_space(1))) void*)g,
      (__attribute__((address_space(3))) void*)l, 16, 0, 0);
}

__device__ inline unsigned int pack2(float lo, float hi) {
  unsigned int ulo = __float_as_uint(lo), uhi = __float_as_uint(hi);
  return (uhi & 0xFFFF0000u) | (ulo >> 16);
}
__device__ inline unsigned short f2bf_r(float f) {
  return (unsigned short)((__float_as_uint(f) + 0x8000u) >> 16);
}
__device__ inline float bf2f(unsigned short h) {
  return __uint_as_float(((unsigned int)h) << 16);
}

// ---------- K0: merged weight repack ----------
// blocks 0..95:   W1 [3,2048,128] f32 -> W1bt [384,2048] bf16 (B^T, k-contiguous)
// blocks 96..287: W2 [3,128,128] f32  -> W2t  [j][d][c]  bf16 (transposed)
__global__ __launch_bounds__(256) void k_repack(const float* __restrict__ W1,
                                                const float* __restrict__ W2,
                                                unsigned short* __restrict__ W1bt,
                                                unsigned short* __restrict__ W2t) {
  __shared__ float tile[64 * 128];   // 32 KB
  const int b = blockIdx.x, tid = threadIdx.x;
  if (b < 96) {
    const int k = b >> 5, et = b & 31;
    const int e0 = et * 64;
    const float* src = W1 + (size_t)k * 262144 + (size_t)e0 * 128;
#pragma unroll
    for (int i = 0; i < 8; ++i) {
      int idx4 = tid + i * 256;
      ((f32x4*)tile)[idx4] = ((const f32x4*)src)[idx4];
    }
    __syncthreads();
#pragma unroll
    for (int i = 0; i < 4; ++i) {
      int item = tid + i * 256;
      int c = item >> 3, eo = (item & 7) * 8;
      union { unsigned short h[8]; uint4 v; } t;
#pragma unroll
      for (int u = 0; u < 8; ++u) t.h[u] = f2bf_r(tile[(eo + u) * 128 + c]);
      *(uint4*)(W1bt + (size_t)(k * 128 + c) * 2048 + e0 + eo) = t.v;
    }
  } else {
    int idx = (b - 96) * 256 + tid;                 // 49152
    int j = idx >> 14, r = idx & 16383, d = r >> 7, c = r & 127;
    W2t[idx] = f2bf_r(W2[(size_t)j * 16384 + (size_t)c * 128 + d]);
  }
}

// ---------- K1: fused stage1 GEMM + tap-sum/tanh + stage2 GEMM + log-softmax ----------
// 512 blocks x 512 threads (8 waves), 64 out rows/block, 2 blocks/CU -> 16 waves/CU
// (4 waves/SIMD). Round-0 LDS layout + drain schedule, UNCHANGED; the only structural
// change vs the 423-us baseline is occupancy: 8 waves split the 384 cols (48 each,
// acc 5x3), doubling waves/SIMD 2->4 to hide the per-wave latency chain that held
// rounds 0-4 at a constant ~170 us regardless of bytes/pattern/schedule.
__global__ __launch_bounds__(512, 4) void k_fused(const float* __restrict__ X,
                                                  const unsigned short* __restrict__ Bt,
                                                  const unsigned short* __restrict__ W2t,
                                                  const float* __restrict__ b1,
                                                  const float* __restrict__ b2,
                                                  float* __restrict__ out) {
  __shared__ __align__(16) char smem[66560];
  float* Alds = (float*)smem;                             // 68 rows x 256B, chunk c at c^(i&15)
  unsigned short* Blds = (unsigned short*)(smem + 17408); // 384 cols x 128B, chunk c at c^(col&7)
  unsigned short* Yt = (unsigned short*)smem;             // phase B: 80 x 392 bf16 (62,720 B)
  float* zbuf = (float*)(smem + 62720);                   // 2 x 128 f32

  const int r0 = blockIdx.x * 64;
  const int tid = threadIdx.x, wave = tid >> 6, lane = tid & 63;
  const int mrow = lane & 15, quad = lane >> 4;

  // ---- stage-1 A staging: 17 loads of 4 rows. wave w: rows w*8+{0..3, 4..7};
  // wave 0 extra: rows 64..67. Alds row i <-> X row r0-4+i (clamped).
  const float* agp[3];
#pragma unroll
  for (int r = 0; r < 2; ++r) {
    int i = wave * 8 + r * 4 + (lane >> 4);
    int g = r0 - 4 + i; if (g < 0) g = 0;             // block 0 halo clamp (masked later)
    int c = (lane & 15) ^ (i & 15);
    agp[r] = X + (size_t)g * 2048 + c * 4;
  }
  {
    int i = 64 + (lane >> 4);                         // wave-0 extra: rows 64..67
    int g = r0 - 4 + i; if (g > 32767) g = 32767;     // last-block halo clamp (unused rows)
    int c = (lane & 15) ^ (i & 15);
    agp[2] = X + (size_t)g * 2048 + c * 4;
  }
  // ---- B staging: 48 loads of 8 cols; wave w owns loads w*6..w*6+5.
  const unsigned short* bgp[6];
#pragma unroll
  for (int r = 0; r < 6; ++r) {
    int col = (wave * 6 + r) * 8 + (lane >> 3);
    int c = (lane & 7) ^ (col & 7);
    bgp[r] = Bt + (size_t)col * 2048 + c * 8;
  }

  f32x4 acc[5][3] = {};   // wave: 80 logical rows (5 rt) x 48 cols (3 ct)

  for (int k0 = 0; k0 < 2048; k0 += 64) {
#pragma unroll
    for (int r = 0; r < 2; ++r)
      gl_lds16(agp[r], (char*)Alds + (wave * 8 + r * 4) * 256);
    if (wave == 0) gl_lds16(agp[2], (char*)Alds + 64 * 256);
#pragma unroll
    for (int r = 0; r < 6; ++r)
      gl_lds16(bgp[r], (char*)Blds + (wave * 6 + r) * 1024);
#pragma unroll
    for (int r = 0; r < 3; ++r) agp[r] += 64;
#pragma unroll
    for (int r = 0; r < 6; ++r) bgp[r] += 64;
    __syncthreads();   // drains vmcnt(0) + barrier

#pragma unroll
    for (int s = 0; s < 2; ++s) {
      short8 af[5];
#pragma unroll
      for (int rt = 0; rt < 5; ++rt) {                // rt=4 rows 68..79 read garbage (unused)
        int row = rt * 16 + mrow;
        int c0 = s * 8 + quad * 2;
        const float* base = Alds + row * 64;
        f32x4 x0 = *(const f32x4*)(base + ((c0 ^ mrow) * 4));
        f32x4 x1 = *(const f32x4*)(base + (((c0 + 1) ^ mrow) * 4));
        union { unsigned int u[4]; short8 v; } t;
        t.u[0] = pack2(x0[0], x0[1]); t.u[1] = pack2(x0[2], x0[3]);
        t.u[2] = pack2(x1[0], x1[1]); t.u[3] = pack2(x1[2], x1[3]);
        af[rt] = t.v;
      }
#pragma unroll
      for (int ct = 0; ct < 3; ++ct) {
        int col = wave * 48 + ct * 16 + mrow;         // 48%8==0 -> col&7 == mrow&7 (swizzle ok)
        int ch = (s * 4 + quad) ^ (mrow & 7);
        short8 bf = *(const short8*)(Blds + col * 64 + ch * 8);
#pragma unroll
        for (int rt = 0; rt < 5; ++rt)
          acc[rt][ct] = MFMA16(af[rt], bf, acc[rt][ct]);
      }
    }
    __syncthreads();
  }

  // ---- spill acc -> Yt (bf16). Yt row i <-> Y global row r0-4+i; stride 392 (4-bank shift) ----
#pragma unroll
  for (int rt = 0; rt < 5; ++rt)
#pragma unroll
    for (int ct = 0; ct < 3; ++ct)
#pragma unroll
      for (int rg = 0; rg < 4; ++rg) {
        int l = rt * 16 + quad * 4 + rg;
        int col = wave * 48 + ct * 16 + mrow;
        Yt[l * 392 + col] = f2bf_r(acc[rt][ct][rg]);
      }
  __syncthreads();

  // ---- H[p]=tanh(sum taps + cnt*b1), p in [r0-2, r0+63]; store in-place at dead tap-2 slot ----
  // H[p] slot = Yt[p-r0+2][256+c]. Self-RMW per element: race-free (blk0/blk1 never written).
  for (int idx = tid; idx < 66 * 128; idx += 512) {
    int hl = idx >> 7, c = idx & 127;
    int p = r0 - 2 + hl;
    int i = hl + 2;                                   // tap-0 Yt row
    float h = 0.f;
    if (p >= 0) {
      float s = bf2f(Yt[i * 392 + c]);
      float cnt = 1.f;
      if (p >= 1) { s += bf2f(Yt[(i - 1) * 392 + 128 + c]); cnt += 1.f; }
      if (p >= 2) { s += bf2f(Yt[(i - 2) * 392 + 256 + c]); cnt += 1.f; }
      h = tanhf(fmaf(cnt, b1[c], s));
    }
    Yt[(i - 2) * 392 + 256 + c] = f2bf_r(h);          // = Yt[hl][256+c], holds H[r0-2+hl]
  }
  __syncthreads();

  // ---- stage-2 (waves 0-3): Z rows r0+wave*16..+15; A-frag H row = Yt[wave*16+mrow+j][256+..] ----
  if (wave < 4) {
    f32x4 acc2[8] = {};
#pragma unroll
    for (int j = 0; j < 3; ++j) {
#pragma unroll
      for (int kk = 0; kk < 4; ++kk) {
        short8 a0 = *(const short8*)&Yt[(wave * 16 + mrow + j) * 392 + 256 + kk * 32 + quad * 8];
        const unsigned short* wp = W2t + (size_t)(j * 128 + mrow) * 128 + kk * 32 + quad * 8;
#pragma unroll
        for (int ct = 0; ct < 8; ++ct)
          acc2[ct] = MFMA16(a0, *(const short8*)(wp + ct * 16 * 128), acc2[ct]);
      }
    }

    // ---- log-softmax per row (128 cols = 16 lanes x 8 ct-regs) ----
#pragma unroll
    for (int rg = 0; rg < 4; ++rg) {
      float z[8]; float m = -1e30f;
#pragma unroll
      for (int ct = 0; ct < 8; ++ct) {
        z[ct] = acc2[ct][rg] + 3.f * b2[ct * 16 + mrow];
        m = fmaxf(m, z[ct]);
      }
#pragma unroll
      for (int off = 1; off < 16; off <<= 1) m = fmaxf(m, __shfl_xor(m, off, 64));
      float s = 0.f;
#pragma unroll
      for (int ct = 0; ct < 8; ++ct) s += __expf(z[ct] - m);
#pragma unroll
      for (int off = 1; off < 16; off <<= 1) s += __shfl_xor(s, off, 64);
      float lse = m + __logf(s);
      int grow = r0 + wave * 16 + quad * 4 + rg;
      if (grow >= 2) {
        float* op = out + (size_t)grow * 128 + mrow;
#pragma unroll
        for (int ct = 0; ct < 8; ++ct) op[ct * 16] = z[ct] - lse;
      }
    }
  }

  // ---- fallback rows 0,1 (block 0): Z0 = tanh(Y[row][0:128]+b1) @ W2[0] + b2 ----
  if (blockIdx.x == 0) {
    __syncthreads();
    int row = tid >> 7, d = tid & 127;
    if (tid < 256)
      zbuf[row * 128 + d] = tanhf(bf2f(Yt[(row + 4) * 392 + d]) + b1[d]);  // blk0 cols intact
    __syncthreads();
    float zv = 0.f;
    if (tid < 256) {
      zv = b2[d];
      for (int c = 0; c < 128; ++c)
        zv = fmaf(zbuf[row * 128 + c], bf2f(W2t[(size_t)d * 128 + c]), zv); // W2t[0][d][c]=W2[0][c][d]
    }
    __syncthreads();
    if (tid < 256) zbuf[row * 128 + d] = zv;
    __syncthreads();
    if (tid < 256) {
      float m = -1e30f;
      for (int c = 0; c < 128; ++c) m = fmaxf(m, zbuf[row * 128 + c]);
      float s = 0.f;
      for (int c = 0; c < 128; ++c) s += __expf(zbuf[row * 128 + c] - m);
      out[(size_t)row * 128 + d] = zv - m - __logf(s);
    }
  }
}

// ---------- launch ----------
extern "C" void kernel_launch(void* const* d_in, const int* in_sizes, int n_in,
                              void* d_out, int out_size, void* d_ws, size_t ws_size,
                              hipStream_t stream) {
  const float* X  = (const float*)d_in[0];   // [32768, 1, 2048]
  const float* W1 = (const float*)d_in[1];   // [3, 2048, 128]
  const float* b1 = (const float*)d_in[2];   // [1, 128]
  const float* W2 = (const float*)d_in[3];   // [3, 128, 128]
  const float* b2 = (const float*)d_in[4];   // [1, 128]
  float* out = (float*)d_out;                // [32768, 1, 128] fp32

  unsigned short* W1bt = (unsigned short*)d_ws;                    // 384*2048*2 = 1,572,864
  unsigned short* W2t  = (unsigned short*)((char*)d_ws + 1572864); // 98,304

  k_repack<<<288, 256, 0, stream>>>(W1, W2, W1bt, W2t);
  k_fused<<<512, 512, 0, stream>>>(X, W1bt, W2t, b1, b2, out);
}